// Round 2
// baseline (432.924 us; speedup 1.0000x reference)
//
#include <hip/hip_runtime.h>
#include <cstdint>

typedef _Float16 f16;
typedef _Float16 f16x8 __attribute__((ext_vector_type(8)));
typedef float f32x4 __attribute__((ext_vector_type(4)));
typedef float floatx4 __attribute__((ext_vector_type(4)));

#define KTOT 65664      // 128*513
#define KSTEPS 2052     // KTOT/32
#define DP 544          // padded 513 -> 17*32

__device__ __forceinline__ void gload_lds16(const void* g, void* l) {
  __builtin_amdgcn_global_load_lds(
      (const __attribute__((address_space(1))) void*)g,
      (__attribute__((address_space(3))) void*)l, 16, 0, 0);
}

// ---------------- prep: flat hi/lo, layout [2052][2][128][32] (hi plane, lo plane) ----------------
__global__ void prep_flat(const float* __restrict__ obj_seq, f16* __restrict__ flatHL) {
  int base = blockIdx.x * 1024 + threadIdx.x;
#pragma unroll
  for (int j = 0; j < 4; ++j) {
    int o = base + j * 256;                 // < 2052*4096 exactly
    int kb = o >> 12;
    int rem = o & 4095;
    int bb = rem >> 5;
    int kk = rem & 31;
    int k = kb * 32 + kk;
    int n = k / 513;
    int d = k - n * 513;
    float v = (d < 512) ? obj_seq[(((size_t)(bb << 7) + n) << 9) + d] : (float)n;
    f16 h = (f16)v;
    flatHL[(size_t)kb * 8192 + rem] = h;
    flatHL[(size_t)kb * 8192 + 4096 + rem] = (f16)(v - (float)h);
  }
}

// ---------------- prep: objHi/objLo [B*128][544] and objT16 [B][544][128] ----------------
__global__ void prep_obj(const float* __restrict__ obj_seq, f16* __restrict__ objHi,
                         f16* __restrict__ objLo, f16* __restrict__ objT16) {
  __shared__ f16 tile[32][132];
  int b = blockIdx.x / 17, c = blockIdx.x - 17 * (blockIdx.x / 17);
  int t = threadIdx.x;
  if (c < 16) {
#pragma unroll
    for (int i = 0; i < 16; ++i) {
      int e = t + i * 256;
      int n = e >> 5, dd = e & 31;
      float v = obj_seq[(((size_t)(b << 7) + n) << 9) + (c << 5) + dd];
      f16 h = (f16)v;
      objHi[((size_t)((b << 7) + n)) * DP + (c << 5) + dd] = h;
      objLo[((size_t)((b << 7) + n)) * DP + (c << 5) + dd] = (f16)(v - (float)h);
      tile[dd][n] = h;
    }
    __syncthreads();
#pragma unroll
    for (int i = 0; i < 16; ++i) {
      int e = t + i * 256;
      int dd = e >> 7, n = e & 127;
      objT16[(((size_t)b * DP + (c << 5) + dd) << 7) + n] = tile[dd][n];
    }
  } else {
#pragma unroll
    for (int i = 0; i < 16; ++i) {
      int e = t + i * 256;
      int n = e >> 5, dd = e & 31;
      f16 h = (dd == 0) ? (f16)(float)n : (f16)0.f;
      objHi[((size_t)((b << 7) + n)) * DP + 512 + dd] = h;
      objLo[((size_t)((b << 7) + n)) * DP + 512 + dd] = (f16)0.f;
    }
#pragma unroll
    for (int i = 0; i < 16; ++i) {
      int e = t + i * 256;
      int dd = e >> 7, n = e & 127;
      objT16[(((size_t)b * DP + 512 + dd) << 7) + n] = (dd == 0) ? (f16)(float)n : (f16)0.f;
    }
  }
}

// ---------------- prep: W_k split (scaled by 1024) into f16 hi/lo, [64][544] ----------------
__global__ void prep_wk(const float* __restrict__ W_k, f16* __restrict__ WkHi,
                        f16* __restrict__ WkLo) {
  int o = blockIdx.x * 256 + threadIdx.x;   // < 64*544 exactly (grid 136)
  int kd = o / DP, d = o - kd * DP;
  float v = (d < 513) ? W_k[kd * 513 + d] * 1024.f : 0.f;
  f16 h = (f16)v;
  WkHi[o] = h;
  WkLo[o] = (f16)(v - (float)h);
}

// ---------------- big GEMM: Q[128][4096] += flat @ Wcat^T (split-f16 A x split-f16 W, 3-term) ----------------
__global__ __launch_bounds__(512, 2) void qgemm(const f16* __restrict__ flatHL,
                                                const float* __restrict__ Wq1,
                                                const float* __restrict__ Wq2,
                                                float* __restrict__ Q) {
  __shared__ f16 As[2][8192];               // 2 x 16KB: [hi 128x32 | lo 128x32]
  const int tid = threadIdx.x;
  const int lane = tid & 63;
  const int wave = tid >> 6;
  const int wm = wave >> 2, wn = wave & 3;  // 2(m) x 4(n) waves
  const int l15 = lane & 15, lk = lane >> 4;
  const int ntile = blockIdx.x & 31;
  const int ksp = blockIdx.x >> 5;          // split-K 16
  const int t0 = ksp * 129;
  const int nt = min(129, KSTEPS - t0);
  const float* Wsrc = (ntile < 16) ? (Wq1 + (size_t)ntile * 128 * KTOT)
                                   : (Wq2 + (size_t)(ntile - 16) * 128 * KTOT);
  const float* wrow0 = Wsrc + (size_t)(wn * 32 + l15) * KTOT + (size_t)t0 * 32 + lk * 8;
  const float* wrow1 = wrow0 + (size_t)16 * KTOT;
  const int abyte = (wm * 64 + l15) * 64 + lk * 16;  // LDS byte offset of A hi frag
  const f16* sbase = flatHL + (size_t)t0 * 8192 + tid * 8;

  f32x4 acc[4][2];
#pragma unroll
  for (int mi = 0; mi < 4; ++mi)
#pragma unroll
    for (int nf = 0; nf < 2; ++nf) acc[mi][nf] = (f32x4){0.f, 0.f, 0.f, 0.f};

  gload_lds16(sbase, &As[0][tid * 8]);
  gload_lds16(sbase + 4096, &As[0][4096 + tid * 8]);
  __syncthreads();

  for (int t = 0; t < nt; ++t) {
    const int cur = t & 1;
    floatx4 w0a = *(const floatx4*)(wrow0 + (size_t)t * 32);
    floatx4 w0b = *(const floatx4*)(wrow0 + (size_t)t * 32 + 4);
    floatx4 w1a = *(const floatx4*)(wrow1 + (size_t)t * 32);
    floatx4 w1b = *(const floatx4*)(wrow1 + (size_t)t * 32 + 4);
    if (t + 1 < nt) {
      gload_lds16(sbase + (size_t)(t + 1) * 8192, &As[cur ^ 1][tid * 8]);
      gload_lds16(sbase + (size_t)(t + 1) * 8192 + 4096, &As[cur ^ 1][4096 + tid * 8]);
    }

    f16x8 whi[2], wlo[2];
#pragma unroll
    for (int j = 0; j < 4; ++j) {
      { float v = w0a[j] * 1024.f; f16 h = (f16)v; whi[0][j] = h; wlo[0][j] = (f16)(v - (float)h); }
      { float v = w0b[j] * 1024.f; f16 h = (f16)v; whi[0][4 + j] = h; wlo[0][4 + j] = (f16)(v - (float)h); }
      { float v = w1a[j] * 1024.f; f16 h = (f16)v; whi[1][j] = h; wlo[1][j] = (f16)(v - (float)h); }
      { float v = w1b[j] * 1024.f; f16 h = (f16)v; whi[1][4 + j] = h; wlo[1][4 + j] = (f16)(v - (float)h); }
    }

    f16x8 afh[4], afl[4];
#pragma unroll
    for (int mi = 0; mi < 4; ++mi) {
      afh[mi] = *(const f16x8*)((const char*)&As[cur][0] + abyte + mi * 1024);
      afl[mi] = *(const f16x8*)((const char*)&As[cur][0] + 8192 + abyte + mi * 1024);
    }

#pragma unroll
    for (int mi = 0; mi < 4; ++mi) {
#pragma unroll
      for (int nf = 0; nf < 2; ++nf) {
        acc[mi][nf] = __builtin_amdgcn_mfma_f32_16x16x32_f16(afh[mi], whi[nf], acc[mi][nf], 0, 0, 0);
        acc[mi][nf] = __builtin_amdgcn_mfma_f32_16x16x32_f16(afh[mi], wlo[nf], acc[mi][nf], 0, 0, 0);
        acc[mi][nf] = __builtin_amdgcn_mfma_f32_16x16x32_f16(afl[mi], whi[nf], acc[mi][nf], 0, 0, 0);
      }
    }
    __syncthreads();
  }

  const float s = 1.f / 1024.f;
#pragma unroll
  for (int mi = 0; mi < 4; ++mi) {
    int row = wm * 64 + mi * 16 + lk * 4;
#pragma unroll
    for (int nf = 0; nf < 2; ++nf) {
      int col = ntile * 128 + wn * 32 + nf * 16 + l15;
#pragma unroll
      for (int j = 0; j < 4; ++j) atomicAdd(&Q[(size_t)(row + j) * 4096 + col], acc[mi][nf][j] * s);
    }
  }
}

// ---------------- fused tail: K-proj, scores, softmax, E, output (one block per batch) ----------------
__global__ __launch_bounds__(512, 1) void predinet_tail(
    const f16* __restrict__ objHi, const f16* __restrict__ objLo, const f16* __restrict__ objT16,
    const f16* __restrict__ WkHi, const f16* __restrict__ WkLo,
    const float* __restrict__ Q, const float* __restrict__ W_s, float* __restrict__ out) {
  __shared__ __align__(16) char smem[105984];
  const int b = blockIdx.x;
  const int tid = threadIdx.x, lane = tid & 63, wave = tid >> 6;
  const int l15 = lane & 15, lk = lane >> 4;

  f16* WT = (f16*)(smem);               // [64][136] weights^T; later Ws16 [16][544]
  f16* Qh = (f16*)(smem + 17408);       // [64][72]
  f16* Ql = (f16*)(smem + 26624);       // [64][72]
  f16* Kh = (f16*)(smem + 35840);       // [128][72]
  f16* Kl = (f16*)(smem + 54272);       // [128][72]
  float* S = (float*)(smem + 72704);    // [128][65]
  f16* E = (f16*)(smem + 17408);        // [544][73]  (aliases Qh..S-head after P3)
  float* DL = (float*)(smem + 96832);   // [16][64]   (within dead-S region, past E end)

  // P0: stage Q[b] fp32 -> hi/lo f16
  {
    const float* qsrc = Q + (size_t)b * 4096 + tid * 8;
    floatx4 q0 = *(const floatx4*)qsrc;
    floatx4 q1 = *(const floatx4*)(qsrc + 4);
    int hp = tid >> 3, kd = (tid * 8) & 63;
    f16x8 vh, vl;
#pragma unroll
    for (int j = 0; j < 4; ++j) {
      f16 h0 = (f16)q0[j]; vh[j] = h0; vl[j] = (f16)(q0[j] - (float)h0);
      f16 h1 = (f16)q1[j]; vh[4 + j] = h1; vl[4 + j] = (f16)(q1[j] - (float)h1);
    }
    *(f16x8*)(Qh + hp * 72 + kd) = vh;
    *(f16x8*)(Ql + hp * 72 + kd) = vl;
  }
  // P1: K-GEMM  K[n][kd] = obj @ Wk^T (3-term split), hi/lo f16 out
  {
    f32x4 acc[4];
#pragma unroll
    for (int nf = 0; nf < 4; ++nf) acc[nf] = (f32x4){0.f, 0.f, 0.f, 0.f};
    const f16* arowH = objHi + ((size_t)(b * 128) + wave * 16 + l15) * DP + lk * 8;
    const f16* arowL = objLo + ((size_t)(b * 128) + wave * 16 + l15) * DP + lk * 8;
    const f16* bhi = WkHi + (size_t)l15 * DP + lk * 8;
    const f16* blo = WkLo + (size_t)l15 * DP + lk * 8;
    for (int ks = 0; ks < 17; ++ks) {
      f16x8 ah = *(const f16x8*)(arowH + ks * 32);
      f16x8 al = *(const f16x8*)(arowL + ks * 32);
#pragma unroll
      for (int nf = 0; nf < 4; ++nf) {
        f16x8 h = *(const f16x8*)(bhi + (size_t)nf * 16 * DP + ks * 32);
        f16x8 l = *(const f16x8*)(blo + (size_t)nf * 16 * DP + ks * 32);
        acc[nf] = __builtin_amdgcn_mfma_f32_16x16x32_f16(ah, h, acc[nf], 0, 0, 0);
        acc[nf] = __builtin_amdgcn_mfma_f32_16x16x32_f16(ah, l, acc[nf], 0, 0, 0);
        acc[nf] = __builtin_amdgcn_mfma_f32_16x16x32_f16(al, h, acc[nf], 0, 0, 0);
      }
    }
#pragma unroll
    for (int nf = 0; nf < 4; ++nf)
#pragma unroll
      for (int j = 0; j < 4; ++j) {
        float kv = acc[nf][j] * (1.f / 1024.f);
        f16 h = (f16)kv;
        Kh[(wave * 16 + lk * 4 + j) * 72 + nf * 16 + l15] = h;
        Kl[(wave * 16 + lk * 4 + j) * 72 + nf * 16 + l15] = (f16)(kv - (float)h);
      }
  }
  __syncthreads();
  // P2: scores S[n][h'] = K @ Q^T (3-term split, fp32 out)
  {
    f32x4 acc[4];
#pragma unroll
    for (int nf = 0; nf < 4; ++nf) acc[nf] = (f32x4){0.f, 0.f, 0.f, 0.f};
#pragma unroll
    for (int ks = 0; ks < 2; ++ks) {
      f16x8 ah = *(const f16x8*)(Kh + (wave * 16 + l15) * 72 + ks * 32 + lk * 8);
      f16x8 al = *(const f16x8*)(Kl + (wave * 16 + l15) * 72 + ks * 32 + lk * 8);
#pragma unroll
      for (int nf = 0; nf < 4; ++nf) {
        f16x8 bh = *(const f16x8*)(Qh + (nf * 16 + l15) * 72 + ks * 32 + lk * 8);
        f16x8 bl = *(const f16x8*)(Ql + (nf * 16 + l15) * 72 + ks * 32 + lk * 8);
        acc[nf] = __builtin_amdgcn_mfma_f32_16x16x32_f16(ah, bh, acc[nf], 0, 0, 0);
        acc[nf] = __builtin_amdgcn_mfma_f32_16x16x32_f16(ah, bl, acc[nf], 0, 0, 0);
        acc[nf] = __builtin_amdgcn_mfma_f32_16x16x32_f16(al, bh, acc[nf], 0, 0, 0);
      }
    }
#pragma unroll
    for (int nf = 0; nf < 4; ++nf)
#pragma unroll
      for (int j = 0; j < 4; ++j)
        S[(wave * 16 + lk * 4 + j) * 65 + nf * 16 + l15] = acc[nf][j];
  }
  __syncthreads();
  // P3: softmax over n (wave-parallel, 8 columns per wave); weights -> WT[h'][n] f16
  {
#pragma unroll
    for (int ci = 0; ci < 8; ++ci) {
      int c = wave * 8 + ci;
      float s0 = S[lane * 65 + c], s1 = S[(lane + 64) * 65 + c];
      float m = fmaxf(s0, s1);
      for (int off = 32; off; off >>= 1) m = fmaxf(m, __shfl_xor(m, off));
      float e0 = __expf(s0 - m), e1 = __expf(s1 - m);
      float sum = e0 + e1;
      for (int off = 32; off; off >>= 1) sum += __shfl_xor(sum, off);
      float inv = 1.f / sum;
      WT[c * 136 + lane] = (f16)(e0 * inv);
      WT[c * 136 + 64 + lane] = (f16)(e1 * inv);
    }
  }
  __syncthreads();
  // P4: E^T[d][h'] = obj^T @ weights  (f16 MFMA, fp32 accum, f16 store)
  {
    f16x8 bw[4][4];
#pragma unroll
    for (int nf = 0; nf < 4; ++nf)
#pragma unroll
      for (int ks = 0; ks < 4; ++ks)
        bw[nf][ks] = *(const f16x8*)(WT + (nf * 16 + l15) * 136 + ks * 32 + lk * 8);
    for (int r = 0; r < 5; ++r) {
      int mi = r * 8 + wave;
      if (mi >= 34) break;
      const f16* arow = objT16 + (((size_t)b * DP + mi * 16 + l15) << 7) + lk * 8;
      f16x8 a[4];
#pragma unroll
      for (int ks = 0; ks < 4; ++ks) a[ks] = *(const f16x8*)(arow + ks * 32);
#pragma unroll
      for (int nf = 0; nf < 4; ++nf) {
        f32x4 acc = (f32x4){0.f, 0.f, 0.f, 0.f};
#pragma unroll
        for (int ks = 0; ks < 4; ++ks)
          acc = __builtin_amdgcn_mfma_f32_16x16x32_f16(a[ks], bw[nf][ks], acc, 0, 0, 0);
#pragma unroll
        for (int j = 0; j < 4; ++j)
          E[(mi * 16 + lk * 4 + j) * 73 + nf * 16 + l15] = (f16)acc[j];
      }
    }
  }
  __syncthreads();
  // P5a: W_s -> f16 [16][544] (reuses WT region)
  {
    f16* Ws16 = WT;
    for (int i = tid; i < 16 * DP; i += 512) {
      int r = i / DP, d = i - r * DP;
      Ws16[i] = (f16)((d < 513) ? W_s[r * 513 + d] : 0.f);
    }
  }
  __syncthreads();
  // P5b: DL[r][h'] = sum_d E[d][h'] * Ws[r][d]
  if (wave < 4) {
    const f16* Ws16 = WT;
    f32x4 acc = (f32x4){0.f, 0.f, 0.f, 0.f};
    for (int ks = 0; ks < 17; ++ks) {
      f16x8 a = *(const f16x8*)(Ws16 + l15 * DP + ks * 32 + lk * 8);
      f16x8 bv;
#pragma unroll
      for (int jj = 0; jj < 8; ++jj)
        bv[jj] = E[(ks * 32 + lk * 8 + jj) * 73 + wave * 16 + l15];
      acc = __builtin_amdgcn_mfma_f32_16x16x32_f16(a, bv, acc, 0, 0, 0);
    }
#pragma unroll
    for (int j = 0; j < 4; ++j) DL[(lk * 4 + j) * 64 + wave * 16 + l15] = acc[j];
  }
  __syncthreads();
  // P5c: write output [b][h*18 + r], plus tag channels 16/17
  {
    int h = tid >> 4, r = tid & 15;
    float v = DL[r * 64 + h] - DL[r * 64 + 32 + h];
    out[(size_t)b * 576 + h * 18 + r] = v;
    if (tid < 64) {
      int set = tid >> 5, hh = tid & 31;
      out[(size_t)b * 576 + hh * 18 + 16 + set] = (float)E[512 * 73 + set * 32 + hh];
    }
  }
}

extern "C" void kernel_launch(void* const* d_in, const int* in_sizes, int n_in,
                              void* d_out, int out_size, void* d_ws, size_t ws_size,
                              hipStream_t stream) {
  const float* obj_seq = (const float*)d_in[0];
  const float* W_k = (const float*)d_in[1];
  const float* W_q1 = (const float*)d_in[2];
  const float* W_q2 = (const float*)d_in[3];
  const float* W_s = (const float*)d_in[4];
  float* out = (float*)d_out;

  char* ws = (char*)d_ws;
  size_t off = 0;
  auto carve = [&](size_t bytes) -> char* {
    char* p = ws + off;
    off += (bytes + 255) & ~(size_t)255;
    return p;
  };
  f16* flatHL = (f16*)carve((size_t)KSTEPS * 8192 * 2);    // 33.6 MB
  f16* objHi = (f16*)carve((size_t)16384 * DP * 2);        // 17.8 MB
  f16* objLo = (f16*)carve((size_t)16384 * DP * 2);        // 17.8 MB
  f16* objT16 = (f16*)carve((size_t)128 * DP * 128 * 2);   // 17.8 MB
  f16* WkHi = (f16*)carve((size_t)64 * DP * 2);
  f16* WkLo = (f16*)carve((size_t)64 * DP * 2);
  float* Q = (float*)carve((size_t)128 * 4096 * 4);        // 2 MB
  (void)ws_size; (void)in_sizes; (void)n_in; (void)out_size;

  hipMemsetAsync(Q, 0, (size_t)128 * 4096 * 4, stream);
  prep_flat<<<8208, 256, 0, stream>>>(obj_seq, flatHL);
  prep_obj<<<2176, 256, 0, stream>>>(obj_seq, objHi, objLo, objT16);
  prep_wk<<<136, 256, 0, stream>>>(W_k, WkHi, WkLo);
  qgemm<<<512, 512, 0, stream>>>(flatHL, W_q1, W_q2, Q);
  predinet_tail<<<128, 512, 0, stream>>>(objHi, objLo, objT16, WkHi, WkLo, Q, W_s, out);
}

// Round 3
// 358.272 us; speedup vs baseline: 1.2084x; 1.2084x over previous
//
#include <hip/hip_runtime.h>
#include <cstdint>

typedef _Float16 f16;
typedef _Float16 f16x8 __attribute__((ext_vector_type(8)));
typedef float f32x4 __attribute__((ext_vector_type(4)));
typedef float floatx4 __attribute__((ext_vector_type(4)));

#define KTOT 65664      // 128*513
#define KSTEPS 2052     // KTOT/32
#define DP 544          // padded 513 -> 17*32

__device__ __forceinline__ void gload_lds16(const void* g, void* l) {
  __builtin_amdgcn_global_load_lds(
      (const __attribute__((address_space(1))) void*)g,
      (__attribute__((address_space(3))) void*)l, 16, 0, 0);
}

// ---------------- prep: flat hi/lo, layout [2052][plane 2][k8 4][r 128][8] ----------------
__global__ void prep_flat(const float* __restrict__ obj_seq, f16* __restrict__ flatKM) {
  int base = blockIdx.x * 1024 + threadIdx.x;
#pragma unroll
  for (int j = 0; j < 4; ++j) {
    int o = base + j * 256;                 // < 2052*4096 exactly
    int e = o & 7;
    int r = (o >> 3) & 127;
    int k8 = (o >> 10) & 3;
    int kb = o >> 12;
    int k = kb * 32 + k8 * 8 + e;
    int n = k / 513;
    int d = k - n * 513;
    float v = (d < 512) ? obj_seq[(((size_t)(r << 7) + n) << 9) + d] : (float)n;
    f16 h = (f16)v;
    size_t idx = (size_t)kb * 8192 + k8 * 1024 + r * 8 + e;
    flatKM[idx] = h;
    flatKM[idx + 4096] = (f16)(v - (float)h);
  }
}

// ---------------- prep: objHi/objLo [B*128][544] and objT16 [B][544][128] ----------------
__global__ void prep_obj(const float* __restrict__ obj_seq, f16* __restrict__ objHi,
                         f16* __restrict__ objLo, f16* __restrict__ objT16) {
  __shared__ f16 tile[32][132];
  int b = blockIdx.x / 17, c = blockIdx.x - 17 * (blockIdx.x / 17);
  int t = threadIdx.x;
  if (c < 16) {
#pragma unroll
    for (int i = 0; i < 16; ++i) {
      int e = t + i * 256;
      int n = e >> 5, dd = e & 31;
      float v = obj_seq[(((size_t)(b << 7) + n) << 9) + (c << 5) + dd];
      f16 h = (f16)v;
      objHi[((size_t)((b << 7) + n)) * DP + (c << 5) + dd] = h;
      objLo[((size_t)((b << 7) + n)) * DP + (c << 5) + dd] = (f16)(v - (float)h);
      tile[dd][n] = h;
    }
    __syncthreads();
#pragma unroll
    for (int i = 0; i < 16; ++i) {
      int e = t + i * 256;
      int dd = e >> 7, n = e & 127;
      objT16[(((size_t)b * DP + (c << 5) + dd) << 7) + n] = tile[dd][n];
    }
  } else {
#pragma unroll
    for (int i = 0; i < 16; ++i) {
      int e = t + i * 256;
      int n = e >> 5, dd = e & 31;
      f16 h = (dd == 0) ? (f16)(float)n : (f16)0.f;
      objHi[((size_t)((b << 7) + n)) * DP + 512 + dd] = h;
      objLo[((size_t)((b << 7) + n)) * DP + 512 + dd] = (f16)0.f;
    }
#pragma unroll
    for (int i = 0; i < 16; ++i) {
      int e = t + i * 256;
      int dd = e >> 7, n = e & 127;
      objT16[(((size_t)b * DP + 512 + dd) << 7) + n] = (dd == 0) ? (f16)(float)n : (f16)0.f;
    }
  }
}

// ---------------- prep: W_k split (scaled by 1024) into f16 hi/lo, [64][544] ----------------
__global__ void prep_wk(const float* __restrict__ W_k, f16* __restrict__ WkHi,
                        f16* __restrict__ WkLo) {
  int o = blockIdx.x * 256 + threadIdx.x;   // < 64*544 exactly (grid 136)
  int kd = o / DP, d = o - kd * DP;
  float v = (d < 513) ? W_k[kd * 513 + d] * 1024.f : 0.f;
  f16 h = (f16)v;
  WkHi[o] = h;
  WkLo[o] = (f16)(v - (float)h);
}

// ---------------- big GEMM: ring-4 LDS pipeline, counted vmcnt, raw barriers ----------------
// grid 256 = ntile(32) x ksp(8); 1 block/CU; LDS: A slots 4x16KB + W slots 4x16KB = 128KB
__global__ __launch_bounds__(512, 2) void qgemm(const f16* __restrict__ flatKM,
                                                const float* __restrict__ Wq1,
                                                const float* __restrict__ Wq2,
                                                float* __restrict__ Q) {
  __shared__ __align__(16) char smem[131072];
  const int tid = threadIdx.x;
  const int lane = tid & 63;
  const int wave = tid >> 6;
  const int wm = wave >> 2, wn = wave & 3;  // 2(m) x 4(n) waves
  const int l15 = lane & 15, lk = lane >> 4;
  const int ntile = blockIdx.x & 31;
  const int ksp = blockIdx.x >> 5;          // split-K 8
  const int t0 = ksp * 257;
  const int nt = min(257, KSTEPS - t0);
  const float* Wsrc = (ntile < 16) ? (Wq1 + (size_t)ntile * 128 * KTOT)
                                   : (Wq2 + (size_t)(ntile - 16) * 128 * KTOT);

  // per-thread W staging sources (XOR-(col&7) pre-swizzled so LDS-linear dest == swizzled layout)
  const int col0 = tid >> 3;                    // call0: cols 0..63
  const int kh0 = (tid & 7) ^ (col0 & 7);
  const int col1 = (512 + tid) >> 3;            // call1: cols 64..127
  const int kh1 = (tid & 7) ^ (col1 & 7);
  const float* wsrc0 = Wsrc + (size_t)col0 * KTOT + (size_t)t0 * 32 + kh0 * 4;
  const float* wsrc1 = Wsrc + (size_t)col1 * KTOT + (size_t)t0 * 32 + kh1 * 4;
  const f16* asrc = flatKM + (size_t)t0 * 8192 + tid * 8;

  // per-lane LDS read offsets (within a slot)
  int aoff[4];
#pragma unroll
  for (int mi = 0; mi < 4; ++mi) aoff[mi] = lk * 2048 + (wm * 64 + mi * 16 + l15) * 16;
  int woff[2][2];
#pragma unroll
  for (int nf = 0; nf < 2; ++nf) {
    int col = wn * 32 + nf * 16 + l15;
    int c7 = col & 7;
    woff[nf][0] = col * 128 + ((lk * 2) ^ c7) * 16;
    woff[nf][1] = col * 128 + ((lk * 2 + 1) ^ c7) * 16;
  }

  f32x4 acc[4][2];
#pragma unroll
  for (int mi = 0; mi < 4; ++mi)
#pragma unroll
    for (int nf = 0; nf < 2; ++nf) acc[mi][nf] = (f32x4){0.f, 0.f, 0.f, 0.f};

  auto stage = [&](int tt) {
    char* As = smem + (tt & 3) * 16384;
    char* Ws = smem + 65536 + (tt & 3) * 16384;
    gload_lds16(asrc + (size_t)tt * 8192, As + tid * 16);
    gload_lds16(asrc + (size_t)tt * 8192 + 4096, As + 8192 + tid * 16);
    gload_lds16(wsrc0 + (size_t)tt * 32, Ws + tid * 16);
    gload_lds16(wsrc1 + (size_t)tt * 32, Ws + 8192 + tid * 16);
  };

  // prologue: 3 tiles in flight (12 calls per wave)
  stage(0); stage(1); stage(2);

  for (int t = 0; t < nt; ++t) {
    if (t < nt - 2)       asm volatile("s_waitcnt vmcnt(8)" ::: "memory");
    else if (t == nt - 2) asm volatile("s_waitcnt vmcnt(4)" ::: "memory");
    else                  asm volatile("s_waitcnt vmcnt(0)" ::: "memory");
    __builtin_amdgcn_s_barrier();
    __builtin_amdgcn_sched_barrier(0);
    if (t + 3 < nt) stage(t + 3);

    const char* As = smem + (t & 3) * 16384;
    const char* Ws = smem + 65536 + (t & 3) * 16384;

    f16x8 afh[4], afl[4];
#pragma unroll
    for (int mi = 0; mi < 4; ++mi) {
      afh[mi] = *(const f16x8*)(As + aoff[mi]);
      afl[mi] = *(const f16x8*)(As + 8192 + aoff[mi]);
    }
    floatx4 wv[2][2];
#pragma unroll
    for (int nf = 0; nf < 2; ++nf) {
      wv[nf][0] = *(const floatx4*)(Ws + woff[nf][0]);
      wv[nf][1] = *(const floatx4*)(Ws + woff[nf][1]);
    }

    f16x8 whi[2], wlo[2];
#pragma unroll
    for (int nf = 0; nf < 2; ++nf)
#pragma unroll
      for (int j = 0; j < 4; ++j) {
        { float v = wv[nf][0][j] * 1024.f; f16 h = (f16)v; whi[nf][j] = h; wlo[nf][j] = (f16)(v - (float)h); }
        { float v = wv[nf][1][j] * 1024.f; f16 h = (f16)v; whi[nf][4 + j] = h; wlo[nf][4 + j] = (f16)(v - (float)h); }
      }

#pragma unroll
    for (int mi = 0; mi < 4; ++mi) {
#pragma unroll
      for (int nf = 0; nf < 2; ++nf) {
        acc[mi][nf] = __builtin_amdgcn_mfma_f32_16x16x32_f16(afh[mi], whi[nf], acc[mi][nf], 0, 0, 0);
        acc[mi][nf] = __builtin_amdgcn_mfma_f32_16x16x32_f16(afh[mi], wlo[nf], acc[mi][nf], 0, 0, 0);
        acc[mi][nf] = __builtin_amdgcn_mfma_f32_16x16x32_f16(afl[mi], whi[nf], acc[mi][nf], 0, 0, 0);
      }
    }
  }

  const float s = 1.f / 1024.f;
#pragma unroll
  for (int mi = 0; mi < 4; ++mi) {
    int row = wm * 64 + mi * 16 + lk * 4;
#pragma unroll
    for (int nf = 0; nf < 2; ++nf) {
      int col = ntile * 128 + wn * 32 + nf * 16 + l15;
#pragma unroll
      for (int j = 0; j < 4; ++j) atomicAdd(&Q[(size_t)(row + j) * 4096 + col], acc[mi][nf][j] * s);
    }
  }
}

// ---------------- fused tail: K-proj, scores, softmax, E, output (one block per batch) ----------------
__global__ __launch_bounds__(512, 1) void predinet_tail(
    const f16* __restrict__ objHi, const f16* __restrict__ objLo, const f16* __restrict__ objT16,
    const f16* __restrict__ WkHi, const f16* __restrict__ WkLo,
    const float* __restrict__ Q, const float* __restrict__ W_s, float* __restrict__ out) {
  __shared__ __align__(16) char smem[105984];
  const int b = blockIdx.x;
  const int tid = threadIdx.x, lane = tid & 63, wave = tid >> 6;
  const int l15 = lane & 15, lk = lane >> 4;

  f16* WT = (f16*)(smem);               // [64][136] weights^T; later Ws16 [16][544]
  f16* Qh = (f16*)(smem + 17408);       // [64][72]
  f16* Ql = (f16*)(smem + 26624);       // [64][72]
  f16* Kh = (f16*)(smem + 35840);       // [128][72]
  f16* Kl = (f16*)(smem + 54272);       // [128][72]
  float* S = (float*)(smem + 72704);    // [128][65]
  f16* E = (f16*)(smem + 17408);        // [544][73]  (aliases Qh..S-head after P3)
  float* DL = (float*)(smem + 96832);   // [16][64]

  // P0: stage Q[b] fp32 -> hi/lo f16
  {
    const float* qsrc = Q + (size_t)b * 4096 + tid * 8;
    floatx4 q0 = *(const floatx4*)qsrc;
    floatx4 q1 = *(const floatx4*)(qsrc + 4);
    int hp = tid >> 3, kd = (tid * 8) & 63;
    f16x8 vh, vl;
#pragma unroll
    for (int j = 0; j < 4; ++j) {
      f16 h0 = (f16)q0[j]; vh[j] = h0; vl[j] = (f16)(q0[j] - (float)h0);
      f16 h1 = (f16)q1[j]; vh[4 + j] = h1; vl[4 + j] = (f16)(q1[j] - (float)h1);
    }
    *(f16x8*)(Qh + hp * 72 + kd) = vh;
    *(f16x8*)(Ql + hp * 72 + kd) = vl;
  }
  // P1: K-GEMM  K[n][kd] = obj @ Wk^T (3-term split), hi/lo f16 out
  {
    f32x4 acc[4];
#pragma unroll
    for (int nf = 0; nf < 4; ++nf) acc[nf] = (f32x4){0.f, 0.f, 0.f, 0.f};
    const f16* arowH = objHi + ((size_t)(b * 128) + wave * 16 + l15) * DP + lk * 8;
    const f16* arowL = objLo + ((size_t)(b * 128) + wave * 16 + l15) * DP + lk * 8;
    const f16* bhi = WkHi + (size_t)l15 * DP + lk * 8;
    const f16* blo = WkLo + (size_t)l15 * DP + lk * 8;
    for (int ks = 0; ks < 17; ++ks) {
      f16x8 ah = *(const f16x8*)(arowH + ks * 32);
      f16x8 al = *(const f16x8*)(arowL + ks * 32);
#pragma unroll
      for (int nf = 0; nf < 4; ++nf) {
        f16x8 h = *(const f16x8*)(bhi + (size_t)nf * 16 * DP + ks * 32);
        f16x8 l = *(const f16x8*)(blo + (size_t)nf * 16 * DP + ks * 32);
        acc[nf] = __builtin_amdgcn_mfma_f32_16x16x32_f16(ah, h, acc[nf], 0, 0, 0);
        acc[nf] = __builtin_amdgcn_mfma_f32_16x16x32_f16(ah, l, acc[nf], 0, 0, 0);
        acc[nf] = __builtin_amdgcn_mfma_f32_16x16x32_f16(al, h, acc[nf], 0, 0, 0);
      }
    }
#pragma unroll
    for (int nf = 0; nf < 4; ++nf)
#pragma unroll
      for (int j = 0; j < 4; ++j) {
        float kv = acc[nf][j] * (1.f / 1024.f);
        f16 h = (f16)kv;
        Kh[(wave * 16 + lk * 4 + j) * 72 + nf * 16 + l15] = h;
        Kl[(wave * 16 + lk * 4 + j) * 72 + nf * 16 + l15] = (f16)(kv - (float)h);
      }
  }
  __syncthreads();
  // P2: scores S[n][h'] = K @ Q^T (3-term split, fp32 out)
  {
    f32x4 acc[4];
#pragma unroll
    for (int nf = 0; nf < 4; ++nf) acc[nf] = (f32x4){0.f, 0.f, 0.f, 0.f};
#pragma unroll
    for (int ks = 0; ks < 2; ++ks) {
      f16x8 ah = *(const f16x8*)(Kh + (wave * 16 + l15) * 72 + ks * 32 + lk * 8);
      f16x8 al = *(const f16x8*)(Kl + (wave * 16 + l15) * 72 + ks * 32 + lk * 8);
#pragma unroll
      for (int nf = 0; nf < 4; ++nf) {
        f16x8 bh = *(const f16x8*)(Qh + (nf * 16 + l15) * 72 + ks * 32 + lk * 8);
        f16x8 bl = *(const f16x8*)(Ql + (nf * 16 + l15) * 72 + ks * 32 + lk * 8);
        acc[nf] = __builtin_amdgcn_mfma_f32_16x16x32_f16(ah, bh, acc[nf], 0, 0, 0);
        acc[nf] = __builtin_amdgcn_mfma_f32_16x16x32_f16(ah, bl, acc[nf], 0, 0, 0);
        acc[nf] = __builtin_amdgcn_mfma_f32_16x16x32_f16(al, bh, acc[nf], 0, 0, 0);
      }
    }
#pragma unroll
    for (int nf = 0; nf < 4; ++nf)
#pragma unroll
      for (int j = 0; j < 4; ++j)
        S[(wave * 16 + lk * 4 + j) * 65 + nf * 16 + l15] = acc[nf][j];
  }
  __syncthreads();
  // P3: softmax over n (wave-parallel, 8 columns per wave); weights -> WT[h'][n] f16
  {
#pragma unroll
    for (int ci = 0; ci < 8; ++ci) {
      int c = wave * 8 + ci;
      float s0 = S[lane * 65 + c], s1 = S[(lane + 64) * 65 + c];
      float m = fmaxf(s0, s1);
      for (int off = 32; off; off >>= 1) m = fmaxf(m, __shfl_xor(m, off));
      float e0 = __expf(s0 - m), e1 = __expf(s1 - m);
      float sum = e0 + e1;
      for (int off = 32; off; off >>= 1) sum += __shfl_xor(sum, off);
      float inv = 1.f / sum;
      WT[c * 136 + lane] = (f16)(e0 * inv);
      WT[c * 136 + 64 + lane] = (f16)(e1 * inv);
    }
  }
  __syncthreads();
  // P4: E^T[d][h'] = obj^T @ weights  (f16 MFMA, fp32 accum, f16 store)
  {
    f16x8 bw[4][4];
#pragma unroll
    for (int nf = 0; nf < 4; ++nf)
#pragma unroll
      for (int ks = 0; ks < 4; ++ks)
        bw[nf][ks] = *(const f16x8*)(WT + (nf * 16 + l15) * 136 + ks * 32 + lk * 8);
    for (int r = 0; r < 5; ++r) {
      int mi = r * 8 + wave;
      if (mi >= 34) break;
      const f16* arow = objT16 + (((size_t)b * DP + mi * 16 + l15) << 7) + lk * 8;
      f16x8 a[4];
#pragma unroll
      for (int ks = 0; ks < 4; ++ks) a[ks] = *(const f16x8*)(arow + ks * 32);
#pragma unroll
      for (int nf = 0; nf < 4; ++nf) {
        f32x4 acc = (f32x4){0.f, 0.f, 0.f, 0.f};
#pragma unroll
        for (int ks = 0; ks < 4; ++ks)
          acc = __builtin_amdgcn_mfma_f32_16x16x32_f16(a[ks], bw[nf][ks], acc, 0, 0, 0);
#pragma unroll
        for (int j = 0; j < 4; ++j)
          E[(mi * 16 + lk * 4 + j) * 73 + nf * 16 + l15] = (f16)acc[j];
      }
    }
  }
  __syncthreads();
  // P5a: W_s -> f16 [16][544] (reuses WT region)
  {
    f16* Ws16 = WT;
    for (int i = tid; i < 16 * DP; i += 512) {
      int r = i / DP, d = i - r * DP;
      Ws16[i] = (f16)((d < 513) ? W_s[r * 513 + d] : 0.f);
    }
  }
  __syncthreads();
  // P5b: DL[r][h'] = sum_d E[d][h'] * Ws[r][d]
  if (wave < 4) {
    const f16* Ws16 = WT;
    f32x4 acc = (f32x4){0.f, 0.f, 0.f, 0.f};
    for (int ks = 0; ks < 17; ++ks) {
      f16x8 a = *(const f16x8*)(Ws16 + l15 * DP + ks * 32 + lk * 8);
      f16x8 bv;
#pragma unroll
      for (int jj = 0; jj < 8; ++jj)
        bv[jj] = E[(ks * 32 + lk * 8 + jj) * 73 + wave * 16 + l15];
      acc = __builtin_amdgcn_mfma_f32_16x16x32_f16(a, bv, acc, 0, 0, 0);
    }
#pragma unroll
    for (int j = 0; j < 4; ++j) DL[(lk * 4 + j) * 64 + wave * 16 + l15] = acc[j];
  }
  __syncthreads();
  // P5c: write output [b][h*18 + r], plus tag channels 16/17
  {
    int h = tid >> 4, r = tid & 15;
    float v = DL[r * 64 + h] - DL[r * 64 + 32 + h];
    out[(size_t)b * 576 + h * 18 + r] = v;
    if (tid < 64) {
      int set = tid >> 5, hh = tid & 31;
      out[(size_t)b * 576 + hh * 18 + 16 + set] = (float)E[512 * 73 + set * 32 + hh];
    }
  }
}

extern "C" void kernel_launch(void* const* d_in, const int* in_sizes, int n_in,
                              void* d_out, int out_size, void* d_ws, size_t ws_size,
                              hipStream_t stream) {
  const float* obj_seq = (const float*)d_in[0];
  const float* W_k = (const float*)d_in[1];
  const float* W_q1 = (const float*)d_in[2];
  const float* W_q2 = (const float*)d_in[3];
  const float* W_s = (const float*)d_in[4];
  float* out = (float*)d_out;

  char* ws = (char*)d_ws;
  size_t off = 0;
  auto carve = [&](size_t bytes) -> char* {
    char* p = ws + off;
    off += (bytes + 255) & ~(size_t)255;
    return p;
  };
  f16* flatKM = (f16*)carve((size_t)KSTEPS * 8192 * 2);    // 33.6 MB
  f16* objHi = (f16*)carve((size_t)16384 * DP * 2);        // 17.8 MB
  f16* objLo = (f16*)carve((size_t)16384 * DP * 2);        // 17.8 MB
  f16* objT16 = (f16*)carve((size_t)128 * DP * 128 * 2);   // 17.8 MB
  f16* WkHi = (f16*)carve((size_t)64 * DP * 2);
  f16* WkLo = (f16*)carve((size_t)64 * DP * 2);
  float* Q = (float*)carve((size_t)128 * 4096 * 4);        // 2 MB
  (void)ws_size; (void)in_sizes; (void)n_in; (void)out_size;

  hipMemsetAsync(Q, 0, (size_t)128 * 4096 * 4, stream);
  prep_flat<<<8208, 256, 0, stream>>>(obj_seq, flatKM);
  prep_obj<<<2176, 256, 0, stream>>>(obj_seq, objHi, objLo, objT16);
  prep_wk<<<136, 256, 0, stream>>>(W_k, WkHi, WkLo);
  qgemm<<<256, 512, 0, stream>>>(flatKM, W_q1, W_q2, Q);
  predinet_tail<<<128, 512, 0, stream>>>(objHi, objLo, objT16, WkHi, WkLo, Q, W_s, out);
}